// Round 5
// baseline (157.066 us; speedup 1.0000x reference)
//
#include <hip/hip_runtime.h>

// Bilinear warp: out[n,y,x,c] = 4-corner bilinear sample of x at (x+dx, y+dy),
// zero padding outside. N=4, H=W=1024, C=8, fp32.
//
// R9 = R7 structure (76.0 us: 2 lanes/px, 2 px/thread, nt flow loads, nt out
// stores) + NON-TEMPORAL img gathers.
// Post-mortem chain: R3 ILP-neutral, R8 instr-count-halving-neutral(-8%),
// R5/R8 both improved FETCH_SIZE yet slowed down => bound below L2, at the
// per-CU L1/TCP line-service path. Gather L1 hit rate is ~nil (dy i.i.d. per
// pixel => no deterministic line reuse; L1's 256 lines turn over before any
// vertical-neighbor reuse arrives), so L1 allocate+evict on every gather line
// is pure treadmill. nt gathers (no-allocate/evict-first) should cut TCP fill
// occupancy; L2 still captures the statistical reuse.
// Diagnostic outcomes: faster+FETCH flat => L1-occupancy theory confirmed.
// FETCH balloons => nt leaked into L2, revert. Neutral => declare roofline.

typedef float vf2 __attribute__((ext_vector_type(2)));
typedef float vf4 __attribute__((ext_vector_type(4)));

__global__ __launch_bounds__(256) void Warp_41446434406635_kernel(
    const float* __restrict__ img,   // [N, H, W, C]
    const float* __restrict__ flow,  // [N, H, W, 2]
    float* __restrict__ out)         // [N, H, W, C]
{
    const int W = 1024, H = 1024;

    int tid = blockIdx.x * 256 + threadIdx.x;
    int g   = tid >> 1;        // pair-slot index
    int h   = tid & 1;         // channel half: 0 -> c0..3, 1 -> c4..7

    int chunk  = g >> 5;       // 64-pixel chunk (never crosses a row)
    int lane32 = g & 31;
    int pA = (chunk << 6) + lane32;   // pixel A
    int pB = pA + 32;                 // pixel B (same row)

    // ---- flow loads (coalesced; both lanes of a pair read the same 8B) ----
    vf2 fA = __builtin_nontemporal_load(reinterpret_cast<const vf2*>(flow) + pA);
    vf2 fB = __builtin_nontemporal_load(reinterpret_cast<const vf2*>(flow) + pB);

    int xA = pA & (W - 1), yA = (pA >> 10) & (H - 1), nA = pA >> 20;
    int xB = xA + 32;          // same n, same y

    // ---- pixel A address/weight setup ----
    float gxA = (float)xA + fA.x, gyA = (float)yA + fA.y;
    float x0fA = floorf(gxA), y0fA = floorf(gyA);
    int ix0A = (int)x0fA, iy0A = (int)y0fA;
    int ix1A = ix0A + 1,  iy1A = iy0A + 1;
    float wx1A = gxA - x0fA, wy1A = gyA - y0fA;
    float wx0A = 1.0f - wx1A, wy0A = 1.0f - wy1A;
    bool vx0A = (ix0A >= 0) & (ix0A < W);
    bool vx1A = (ix1A >= 0) & (ix1A < W);
    bool vy0A = (iy0A >= 0) & (iy0A < H);
    bool vy1A = (iy1A >= 0) & (iy1A < H);
    float w00A = (vy0A & vx0A) ? wy0A * wx0A : 0.0f;
    float w01A = (vy0A & vx1A) ? wy0A * wx1A : 0.0f;
    float w10A = (vy1A & vx0A) ? wy1A * wx0A : 0.0f;
    float w11A = (vy1A & vx1A) ? wy1A * wx1A : 0.0f;
    int cx0A = min(max(ix0A, 0), W - 1);
    int cx1A = min(max(ix1A, 0), W - 1);
    int cy0A = min(max(iy0A, 0), H - 1);
    int cy1A = min(max(iy1A, 0), H - 1);

    // ---- pixel B address/weight setup ----
    float gxB = (float)xB + fB.x, gyB = (float)yA + fB.y;
    float x0fB = floorf(gxB), y0fB = floorf(gyB);
    int ix0B = (int)x0fB, iy0B = (int)y0fB;
    int ix1B = ix0B + 1,  iy1B = iy0B + 1;
    float wx1B = gxB - x0fB, wy1B = gyB - y0fB;
    float wx0B = 1.0f - wx1B, wy0B = 1.0f - wy1B;
    bool vx0B = (ix0B >= 0) & (ix0B < W);
    bool vx1B = (ix1B >= 0) & (ix1B < W);
    bool vy0B = (iy0B >= 0) & (iy0B < H);
    bool vy1B = (iy1B >= 0) & (iy1B < H);
    float w00B = (vy0B & vx0B) ? wy0B * wx0B : 0.0f;
    float w01B = (vy0B & vx1B) ? wy0B * wx1B : 0.0f;
    float w10B = (vy1B & vx0B) ? wy1B * wx0B : 0.0f;
    float w11B = (vy1B & vx1B) ? wy1B * wx1B : 0.0f;
    int cx0B = min(max(ix0B, 0), W - 1);
    int cx1B = min(max(ix1B, 0), W - 1);
    int cy0B = min(max(iy0B, 0), H - 1);
    int cy1B = min(max(iy1B, 0), H - 1);

    // n*H*W*C = n<<23 ; y*W*C = y<<13 ; x*C = x<<3 ; +4 floats if h==1
    const float* base = img + ((size_t)nA << 23) + (h << 2);

    // ---- issue all 8 independent gathers, non-temporal (L1 no-allocate) ----
    const vf4* q00A = reinterpret_cast<const vf4*>(base + ((size_t)cy0A << 13) + (cx0A << 3));
    const vf4* q01A = reinterpret_cast<const vf4*>(base + ((size_t)cy0A << 13) + (cx1A << 3));
    const vf4* q10A = reinterpret_cast<const vf4*>(base + ((size_t)cy1A << 13) + (cx0A << 3));
    const vf4* q11A = reinterpret_cast<const vf4*>(base + ((size_t)cy1A << 13) + (cx1A << 3));
    const vf4* q00B = reinterpret_cast<const vf4*>(base + ((size_t)cy0B << 13) + (cx0B << 3));
    const vf4* q01B = reinterpret_cast<const vf4*>(base + ((size_t)cy0B << 13) + (cx1B << 3));
    const vf4* q10B = reinterpret_cast<const vf4*>(base + ((size_t)cy1B << 13) + (cx0B << 3));
    const vf4* q11B = reinterpret_cast<const vf4*>(base + ((size_t)cy1B << 13) + (cx1B << 3));
    vf4 a00 = __builtin_nontemporal_load(q00A);
    vf4 a01 = __builtin_nontemporal_load(q01A);
    vf4 a10 = __builtin_nontemporal_load(q10A);
    vf4 a11 = __builtin_nontemporal_load(q11A);
    vf4 b00 = __builtin_nontemporal_load(q00B);
    vf4 b01 = __builtin_nontemporal_load(q01B);
    vf4 b10 = __builtin_nontemporal_load(q10B);
    vf4 b11 = __builtin_nontemporal_load(q11B);

    vf4 oA, oB;
    oA.x = fmaf(w00A, a00.x, fmaf(w01A, a01.x, fmaf(w10A, a10.x, w11A * a11.x)));
    oA.y = fmaf(w00A, a00.y, fmaf(w01A, a01.y, fmaf(w10A, a10.y, w11A * a11.y)));
    oA.z = fmaf(w00A, a00.z, fmaf(w01A, a01.z, fmaf(w10A, a10.z, w11A * a11.z)));
    oA.w = fmaf(w00A, a00.w, fmaf(w01A, a01.w, fmaf(w10A, a10.w, w11A * a11.w)));
    oB.x = fmaf(w00B, b00.x, fmaf(w01B, b01.x, fmaf(w10B, b10.x, w11B * b11.x)));
    oB.y = fmaf(w00B, b00.y, fmaf(w01B, b01.y, fmaf(w10B, b10.y, w11B * b11.y)));
    oB.z = fmaf(w00B, b00.z, fmaf(w01B, b01.z, fmaf(w10B, b10.z, w11B * b11.z)));
    oB.w = fmaf(w00B, b00.w, fmaf(w01B, b01.w, fmaf(w10B, b10.w, w11B * b11.w)));

    // ---- non-temporal stores: out has zero reuse, keep it out of L2 ----
    vf4* o4 = reinterpret_cast<vf4*>(out);
    __builtin_nontemporal_store(oA, o4 + ((size_t)pA << 1) + h);  // contiguous 1 KB across the wave
    __builtin_nontemporal_store(oB, o4 + ((size_t)pB << 1) + h);  // next 1 KB

    (void)H;
}

extern "C" void kernel_launch(void* const* d_in, const int* in_sizes, int n_in,
                              void* d_out, int out_size, void* d_ws, size_t ws_size,
                              hipStream_t stream) {
    const float* x = (const float*)d_in[0];
    const float* u = (const float*)d_in[1];
    float* out = (float*)d_out;

    // 4M px * 2 threads/px / 2 px/thread / 256 = 16384 blocks (exact)
    Warp_41446434406635_kernel<<<16384, 256, 0, stream>>>(x, u, out);
}

// Round 6
// 73.371 us; speedup vs baseline: 2.1407x; 2.1407x over previous
//
#include <hip/hip_runtime.h>

// Bilinear warp: out[n,y,x,c] = 4-corner bilinear sample of x at (x+dx, y+dy),
// zero padding outside. N=4, H=W=1024, C=8, fp32.
//
// R10 = R7 (76.0 us best: 2 lanes/px, 2 px/thread, nt flow loads, nt out
// stores) + sc0 (L1-bypass, L2-allocate) img gathers via inline asm.
// R9 taught: nt loads defeat L2 allocation -> FETCH 150->273 MiB, 157 us.
// L2 capture of gather reuse is load-bearing. This round runs the experiment
// R9 intended: skip only the L1 allocate/evict treadmill (gather lines have
// ~zero L1 reuse beyond the intra-pixel x0/x1 pair; dy i.i.d. turns over
// L1's 256 lines before cross-pixel reuse arrives) while L2 still caches.
// sc0 on global_load = coherent load: serviced from L2, no L1 allocation.
// Inline asm since no per-load HIP builtin exposes sc0; manual
// s_waitcnt vmcnt(0) + sched_barrier(0) before the FMA block (rule #18).
// Outcomes: faster+FETCH flat => L1-treadmill confirmed. Neutral => TCP
// request-rate floor, declare roofline. Slower => L1 hits were load-bearing.

typedef float vf2 __attribute__((ext_vector_type(2)));
typedef float vf4 __attribute__((ext_vector_type(4)));

#define GATHER_SC0(dst, ptr) \
    asm volatile("global_load_dwordx4 %0, %1, off sc0" : "=&v"(dst) : "v"(ptr))

__global__ __launch_bounds__(256) void Warp_41446434406635_kernel(
    const float* __restrict__ img,   // [N, H, W, C]
    const float* __restrict__ flow,  // [N, H, W, 2]
    float* __restrict__ out)         // [N, H, W, C]
{
    const int W = 1024, H = 1024;

    int tid = blockIdx.x * 256 + threadIdx.x;
    int g   = tid >> 1;        // pair-slot index
    int h   = tid & 1;         // channel half: 0 -> c0..3, 1 -> c4..7

    int chunk  = g >> 5;       // 64-pixel chunk (never crosses a row)
    int lane32 = g & 31;
    int pA = (chunk << 6) + lane32;   // pixel A
    int pB = pA + 32;                 // pixel B (same row)

    // ---- flow loads (coalesced; both lanes of a pair read the same 8B) ----
    vf2 fA = __builtin_nontemporal_load(reinterpret_cast<const vf2*>(flow) + pA);
    vf2 fB = __builtin_nontemporal_load(reinterpret_cast<const vf2*>(flow) + pB);

    int xA = pA & (W - 1), yA = (pA >> 10) & (H - 1), nA = pA >> 20;
    int xB = xA + 32;          // same n, same y

    // ---- pixel A address/weight setup ----
    float gxA = (float)xA + fA.x, gyA = (float)yA + fA.y;
    float x0fA = floorf(gxA), y0fA = floorf(gyA);
    int ix0A = (int)x0fA, iy0A = (int)y0fA;
    int ix1A = ix0A + 1,  iy1A = iy0A + 1;
    float wx1A = gxA - x0fA, wy1A = gyA - y0fA;
    float wx0A = 1.0f - wx1A, wy0A = 1.0f - wy1A;
    bool vx0A = (ix0A >= 0) & (ix0A < W);
    bool vx1A = (ix1A >= 0) & (ix1A < W);
    bool vy0A = (iy0A >= 0) & (iy0A < H);
    bool vy1A = (iy1A >= 0) & (iy1A < H);
    float w00A = (vy0A & vx0A) ? wy0A * wx0A : 0.0f;
    float w01A = (vy0A & vx1A) ? wy0A * wx1A : 0.0f;
    float w10A = (vy1A & vx0A) ? wy1A * wx0A : 0.0f;
    float w11A = (vy1A & vx1A) ? wy1A * wx1A : 0.0f;
    int cx0A = min(max(ix0A, 0), W - 1);
    int cx1A = min(max(ix1A, 0), W - 1);
    int cy0A = min(max(iy0A, 0), H - 1);
    int cy1A = min(max(iy1A, 0), H - 1);

    // ---- pixel B address/weight setup ----
    float gxB = (float)xB + fB.x, gyB = (float)yA + fB.y;
    float x0fB = floorf(gxB), y0fB = floorf(gyB);
    int ix0B = (int)x0fB, iy0B = (int)y0fB;
    int ix1B = ix0B + 1,  iy1B = iy0B + 1;
    float wx1B = gxB - x0fB, wy1B = gyB - y0fB;
    float wx0B = 1.0f - wx1B, wy0B = 1.0f - wy1B;
    bool vx0B = (ix0B >= 0) & (ix0B < W);
    bool vx1B = (ix1B >= 0) & (ix1B < W);
    bool vy0B = (iy0B >= 0) & (iy0B < H);
    bool vy1B = (iy1B >= 0) & (iy1B < H);
    float w00B = (vy0B & vx0B) ? wy0B * wx0B : 0.0f;
    float w01B = (vy0B & vx1B) ? wy0B * wx1B : 0.0f;
    float w10B = (vy1B & vx0B) ? wy1B * wx0B : 0.0f;
    float w11B = (vy1B & vx1B) ? wy1B * wx1B : 0.0f;
    int cx0B = min(max(ix0B, 0), W - 1);
    int cx1B = min(max(ix1B, 0), W - 1);
    int cy0B = min(max(iy0B, 0), H - 1);
    int cy1B = min(max(iy1B, 0), H - 1);

    // n*H*W*C = n<<23 ; y*W*C = y<<13 ; x*C = x<<3 ; +4 floats if h==1
    const float* base = img + ((size_t)nA << 23) + (h << 2);

    const float* p00A = base + ((size_t)cy0A << 13) + (cx0A << 3);
    const float* p01A = base + ((size_t)cy0A << 13) + (cx1A << 3);
    const float* p10A = base + ((size_t)cy1A << 13) + (cx0A << 3);
    const float* p11A = base + ((size_t)cy1A << 13) + (cx1A << 3);
    const float* p00B = base + ((size_t)cy0B << 13) + (cx0B << 3);
    const float* p01B = base + ((size_t)cy0B << 13) + (cx1B << 3);
    const float* p10B = base + ((size_t)cy1B << 13) + (cx0B << 3);
    const float* p11B = base + ((size_t)cy1B << 13) + (cx1B << 3);

    // ---- issue all 8 independent gathers with sc0 (L1-bypass, L2-alloc) ----
    vf4 a00, a01, a10, a11, b00, b01, b10, b11;
    GATHER_SC0(a00, p00A);
    GATHER_SC0(a01, p01A);
    GATHER_SC0(a10, p10A);
    GATHER_SC0(a11, p11A);
    GATHER_SC0(b00, p00B);
    GATHER_SC0(b01, p01B);
    GATHER_SC0(b10, p10B);
    GATHER_SC0(b11, p11B);

    // manual drain: compiler does not track inline-asm vmem loads.
    asm volatile("s_waitcnt vmcnt(0)" ::: "memory");
    __builtin_amdgcn_sched_barrier(0);   // rule #18: stop hoist of reg-only FMAs

    vf4 oA, oB;
    oA.x = fmaf(w00A, a00.x, fmaf(w01A, a01.x, fmaf(w10A, a10.x, w11A * a11.x)));
    oA.y = fmaf(w00A, a00.y, fmaf(w01A, a01.y, fmaf(w10A, a10.y, w11A * a11.y)));
    oA.z = fmaf(w00A, a00.z, fmaf(w01A, a01.z, fmaf(w10A, a10.z, w11A * a11.z)));
    oA.w = fmaf(w00A, a00.w, fmaf(w01A, a01.w, fmaf(w10A, a10.w, w11A * a11.w)));
    oB.x = fmaf(w00B, b00.x, fmaf(w01B, b01.x, fmaf(w10B, b10.x, w11B * b11.x)));
    oB.y = fmaf(w00B, b00.y, fmaf(w01B, b01.y, fmaf(w10B, b10.y, w11B * b11.y)));
    oB.z = fmaf(w00B, b00.z, fmaf(w01B, b01.z, fmaf(w10B, b10.z, w11B * b11.z)));
    oB.w = fmaf(w00B, b00.w, fmaf(w01B, b01.w, fmaf(w10B, b10.w, w11B * b11.w)));

    // ---- non-temporal stores: out has zero reuse, keep it out of L2 ----
    vf4* o4 = reinterpret_cast<vf4*>(out);
    __builtin_nontemporal_store(oA, o4 + ((size_t)pA << 1) + h);  // contiguous 1 KB across the wave
    __builtin_nontemporal_store(oB, o4 + ((size_t)pB << 1) + h);  // next 1 KB

    (void)H;
}

extern "C" void kernel_launch(void* const* d_in, const int* in_sizes, int n_in,
                              void* d_out, int out_size, void* d_ws, size_t ws_size,
                              hipStream_t stream) {
    const float* x = (const float*)d_in[0];
    const float* u = (const float*)d_in[1];
    float* out = (float*)d_out;

    // 4M px * 2 threads/px / 2 px/thread / 256 = 16384 blocks (exact)
    Warp_41446434406635_kernel<<<16384, 256, 0, stream>>>(x, u, out);
}